// Round 4
// baseline (2275.194 us; speedup 1.0000x reference)
//
#include <hip/hip_runtime.h>

#define V    50000
#define Bn   512
#define Ln   512
#define Hh   100     // per-direction hidden == EMB
#define G4   400     // 4*H gate rows
#define KK   20
#define NEGC -1e6f

// ---------------------------------------------------------------------------
// Kernel 1: vocabulary projection table (one direction).
// table[v][j] = emb[v,:].Wih[j,:] + b[j]   (GEMM M=50000, N=400, K=100)
// ---------------------------------------------------------------------------
__global__ __launch_bounds__(256) void proj_kernel(
    const float* __restrict__ emb,
    const float* __restrict__ Wih, const float* __restrict__ bias,
    float* __restrict__ out)
{
    const int v0 = blockIdx.x * 64;
    const int j0 = blockIdx.y * 64;

    __shared__ float As[100 * 68];   // [k][v], stride 68 (%32==4 -> b128 conflict-free)
    __shared__ float Bs[100 * 68];   // [k][j]
    const int tid = threadIdx.x;

    for (int i = tid; i < 6400; i += 256) {
        int r = i / 100;
        int k = i - r * 100;
        As[k * 68 + r] = (v0 + r < V)  ? emb[(size_t)(v0 + r) * 100 + k] : 0.f;
        Bs[k * 68 + r] = (j0 + r < G4) ? Wih[(j0 + r) * 100 + k]         : 0.f;
    }
    __syncthreads();

    const int tm = tid >> 4, tn = tid & 15;
    float acc[4][4];
#pragma unroll
    for (int i = 0; i < 4; ++i)
#pragma unroll
        for (int j = 0; j < 4; ++j) acc[i][j] = 0.f;

#pragma unroll 4
    for (int k = 0; k < 100; ++k) {
        float4 a = *(const float4*)&As[k * 68 + tm * 4];
        float4 b = *(const float4*)&Bs[k * 68 + tn * 4];
        acc[0][0] = fmaf(a.x, b.x, acc[0][0]); acc[0][1] = fmaf(a.x, b.y, acc[0][1]);
        acc[0][2] = fmaf(a.x, b.z, acc[0][2]); acc[0][3] = fmaf(a.x, b.w, acc[0][3]);
        acc[1][0] = fmaf(a.y, b.x, acc[1][0]); acc[1][1] = fmaf(a.y, b.y, acc[1][1]);
        acc[1][2] = fmaf(a.y, b.z, acc[1][2]); acc[1][3] = fmaf(a.y, b.w, acc[1][3]);
        acc[2][0] = fmaf(a.z, b.x, acc[2][0]); acc[2][1] = fmaf(a.z, b.y, acc[2][1]);
        acc[2][2] = fmaf(a.z, b.z, acc[2][2]); acc[2][3] = fmaf(a.z, b.w, acc[2][3]);
        acc[3][0] = fmaf(a.w, b.x, acc[3][0]); acc[3][1] = fmaf(a.w, b.y, acc[3][1]);
        acc[3][2] = fmaf(a.w, b.z, acc[3][2]); acc[3][3] = fmaf(a.w, b.w, acc[3][3]);
    }

#pragma unroll
    for (int i = 0; i < 4; ++i) {
        int v = v0 + tm * 4 + i;
        if (v < V) {
#pragma unroll
            for (int j = 0; j < 4; ++j) {
                int jj = j0 + tn * 4 + j;
                if (jj < G4) out[(size_t)v * G4 + jj] = acc[i][j] + bias[jj];
            }
        }
    }
}

// ---------------------------------------------------------------------------
// Kernel 2: LSTM recurrence, one direction. One block per batch element.
// 256 threads. Thread t owns gate row t (w0) and, for t<144, gate row 256+t
// (w1) of Whh in VGPRs. Threads 144..193 instead hold W1[t-144][dir*100..+100]
// in w1 and accumulate z = h_new . W1row (fused MLP first layer), one step
// delayed (z for pos_{s-1} rides the readlane sweep of step s).
// dir=0 stores z; dir=1 accumulates into the same buffer (z += ...).
// h broadcast via v_readlane (1 readlane : 2 FMA). Steps >= len are dead code
// in the reference and skipped.
// ---------------------------------------------------------------------------
__device__ __forceinline__ float sigf(float x) { return 1.f / (1.f + expf(-x)); }
__device__ __forceinline__ float tanhfast(float x) { return 1.f - 2.f / (expf(2.f * x) + 1.f); }

__global__ __launch_bounds__(256, 2) void lstm_kernel(
    const int* __restrict__ X, const int* __restrict__ lens,
    const float* __restrict__ proj, const float* __restrict__ Whh,
    const float* __restrict__ W1,
    const float* __restrict__ h0, const float* __restrict__ c0,
    const int dir, float* __restrict__ z)
{
    const int bid = blockIdx.x;
    const int b   = (bid < 256) ? bid : (767 - bid);   // pair long+short lens per CU
    const int len = lens[b];
    const int t   = threadIdx.x;
    const bool zth = (t >= 144 && t < 194);

    // ---- weights into registers ----
    float w0[100], w1[100];
    {
        const float4* W4 = (const float4*)(Whh + t * 100);
#pragma unroll
        for (int i = 0; i < 25; ++i) {
            float4 q = W4[i];
            w0[4*i] = q.x; w0[4*i+1] = q.y; w0[4*i+2] = q.z; w0[4*i+3] = q.w;
        }
        const float* src = (t < 144) ? (Whh + (256 + t) * 100)
                         : (t < 194) ? (W1 + (size_t)(t - 144) * 200 + dir * 100)
                                     : (Whh + 256 * 100);   // clamped, result unused
        const float4* W4b = (const float4*)src;
#pragma unroll
        for (int i = 0; i < 25; ++i) {
            float4 q = W4b[i];
            w1[4*i] = q.x; w1[4*i+1] = q.y; w1[4*i+2] = q.z; w1[4*i+3] = q.w;
        }
    }

    __shared__ float h_s[100];
    __shared__ float g_s[400];
    float c = 0.f;
    if (t < 100) {
        int base = (dir * Bn + b) * Hh + t;
        c = c0[base];
        h_s[t] = h0[base];
    }
    __syncthreads();

    const int lane = t & 63;
    int pos = dir ? (len - 1) : 0;
    int prevpos = 0;

    int tok0 = X[b * Ln + pos];
    const float* pr0 = proj + (size_t)tok0 * G4;
    float pa0 = pr0[t];
    float pa1 = (t < 144) ? pr0[256 + t] : 0.f;

    for (int step = 0; step < len; ++step) {
        int posn = (step + 1 < len) ? (dir ? (len - 2 - step) : (step + 1)) : pos;
        int tokn = X[b * Ln + posn];

        // dir=1: issue accumulate-read early so latency hides under the sweep
        float zprev = 0.f;
        if (dir && zth && step > 0)
            zprev = z[((size_t)b * Ln + prevpos) * 50 + (t - 144)];

        float vh0 = h_s[lane];                       // unconditional: readlane needs
        float vh1 = h_s[lane < 36 ? 64 + lane : 0];  // every lane's register valid

        float acc0 = pa0, acc1 = pa1;
#pragma unroll
        for (int k = 0; k < 100; ++k) {
            float hk = __int_as_float(
                __builtin_amdgcn_readlane(__float_as_int(k < 64 ? vh0 : vh1), k & 63));
            acc0 = fmaf(hk, w0[k], acc0);
            acc1 = fmaf(hk, w1[k], acc1);
        }

        g_s[t] = acc0;
        if (t < 144) {
            g_s[256 + t] = acc1;
        } else if (zth && step > 0) {
            z[((size_t)b * Ln + prevpos) * 50 + (t - 144)] = acc1 + zprev;
        }
        __syncthreads();

        // prefetch next proj row under the update phase
        const float* prn = proj + (size_t)tokn * G4;
        float pan0 = prn[t];
        float pan1 = (t < 144) ? prn[256 + t] : 0.f;

        if (t < 100) {
            float gi = g_s[t], gf = g_s[100 + t], gg = g_s[200 + t], go = g_s[300 + t];
            float si = sigf(gi), sf = sigf(gf), so = sigf(go);
            float tg = tanhfast(gg);
            c = sf * c + si * tg;
            h_s[t] = so * tanhfast(c);
        }
        __syncthreads();

        pa0 = pan0; pa1 = pan1; prevpos = pos; pos = posn;
    }

    // epilogue: z for the final position (all lanes run the sweep; only
    // z-threads store — readlane ignores EXEC, so vh loads must be universal)
    {
        float zprev = 0.f;
        if (dir && zth)
            zprev = z[((size_t)b * Ln + pos) * 50 + (t - 144)];
        float vh0 = h_s[lane];
        float vh1 = h_s[lane < 36 ? 64 + lane : 0];
        float acc1 = 0.f;
#pragma unroll
        for (int k = 0; k < 100; ++k) {
            float hk = __int_as_float(
                __builtin_amdgcn_readlane(__float_as_int(k < 64 ? vh0 : vh1), k & 63));
            acc1 = fmaf(hk, w1[k], acc1);
        }
        if (zth)
            z[((size_t)b * Ln + pos) * 50 + (t - 144)] = acc1 + zprev;
    }
}

// ---------------------------------------------------------------------------
// Kernel 3: tiny MLP tail. probs = relu(zsum+b1) @ W2^T + b2, t < len only.
// One thread per (b,t). W2/b1/b2 accesses are thread-uniform -> s_loads.
// No LDS at all.
// ---------------------------------------------------------------------------
__global__ __launch_bounds__(256) void mlp_kernel(
    const int* __restrict__ lens,
    const float* __restrict__ zsum,
    const float* __restrict__ b1, const float* __restrict__ W2,
    const float* __restrict__ b2, float* __restrict__ probs)
{
    const int gid = blockIdx.x * 256 + threadIdx.x;   // = b*512 + t
    const int b = gid >> 9, t = gid & 511;
    if (t >= lens[b]) return;

    float h[50];
    const float2* f2 = (const float2*)(zsum + (size_t)gid * 50);
#pragma unroll
    for (int j = 0; j < 25; ++j) {
        float2 a = f2[j];
        h[2*j]   = fmaxf(a.x + b1[2*j],   0.f);
        h[2*j+1] = fmaxf(a.y + b1[2*j+1], 0.f);
    }

    float o[20];
#pragma unroll
    for (int oo = 0; oo < 20; ++oo) {
        float acc = b2[oo];
#pragma unroll
        for (int j = 0; j < 50; ++j) acc = fmaf(h[j], W2[oo * 50 + j], acc);
        o[oo] = acc;
    }

    float4* P = (float4*)(probs + (size_t)gid * 20);
#pragma unroll
    for (int q = 0; q < 5; ++q)
        P[q] = make_float4(o[4*q], o[4*q+1], o[4*q+2], o[4*q+3]);
}

// ---------------------------------------------------------------------------
// Kernel 4: Viterbi. One wave per batch row; lanes 0..19 = tags.
// idx matrix in LDS; strict '>' ascending == jnp.argmax first-max.
// ---------------------------------------------------------------------------
__global__ __launch_bounds__(64) void viterbi_kernel(
    const float* __restrict__ probs, const int* __restrict__ lens,
    const float* __restrict__ trans, float* __restrict__ out)
{
    const int b    = blockIdx.x;
    const int lane = threadIdx.x;
    const int len  = lens[b];
    __shared__ unsigned char idx_s[Ln * KK];

    float tcol[20];
#pragma unroll
    for (int i = 0; i < 20; ++i)
        tcol[i] = (lane < 20) ? trans[i * 20 + lane] : 0.f;

    float alpha = (lane == 18) ? 0.f : NEGC;   // START = 18

    for (int t = 0; t < len; ++t) {
        float pv = (lane < 20) ? probs[((size_t)b * Ln + t) * KK + lane] : 0.f;
        float best = -3.4e38f; int bi = 0;
#pragma unroll
        for (int i = 0; i < 20; ++i) {
            float ai = __int_as_float(__builtin_amdgcn_readlane(__float_as_int(alpha), i));
            float v = ai + tcol[i];
            if (v > best) { best = v; bi = i; }
        }
        alpha = best + pv;
        if (lane < 20) idx_s[t * 20 + lane] = (unsigned char)bi;
    }

    float fin = alpha + ((lane < 20) ? trans[lane * 20 + 19] : 0.f);  // END = 19
    float best = -3.4e38f; int cur = 0;
#pragma unroll
    for (int j = 0; j < 20; ++j) {
        float v = __int_as_float(__builtin_amdgcn_readlane(__float_as_int(fin), j));
        if (v > best) { best = v; cur = j; }
    }
    if (lane == 0) out[b] = best;

    float* pout = out + Bn + (size_t)b * Ln;
    for (int tt = len + lane; tt < Ln; tt += 64) pout[tt] = -1.f;  // pads
    __syncthreads();

    if (lane == 0) {
        int c = cur;
        for (int t = len - 1; t >= 0; --t) {
            pout[t] = (float)c;
            c = idx_s[t * 20 + c];
        }
    }
}

// ---------------------------------------------------------------------------
extern "C" void kernel_launch(void* const* d_in, const int* in_sizes, int n_in,
                              void* d_out, int out_size, void* d_ws, size_t ws_size,
                              hipStream_t stream)
{
    const int*   X     = (const int*)  d_in[0];
    const int*   lens  = (const int*)  d_in[1];
    const float* emb   = (const float*)d_in[2];
    const float* WihF  = (const float*)d_in[3];
    const float* WhhF  = (const float*)d_in[4];
    const float* bF    = (const float*)d_in[5];
    const float* WihB  = (const float*)d_in[6];
    const float* WhhB  = (const float*)d_in[7];
    const float* bB    = (const float*)d_in[8];
    const float* h0    = (const float*)d_in[9];
    const float* c0    = (const float*)d_in[10];
    const float* W1    = (const float*)d_in[11];
    const float* b1    = (const float*)d_in[12];
    const float* W2    = (const float*)d_in[13];
    const float* b2    = (const float*)d_in[14];
    const float* trans = (const float*)d_in[15];
    float* out = (float*)d_out;

    // Workspace (floats): proj 20.0M (80 MB, rebuilt per dir; probs aliases it
    // after both LSTMs) | zsum 13.1M (52.4 MB).  Peak = 132.4 MB of d_ws.
    float* ws    = (float*)d_ws;
    float* proj  = ws;
    float* zsum  = ws + (size_t)V * G4;                    // +20,000,000 floats
    float* probs = ws;                                     // alias proj region

    proj_kernel<<<dim3(782, 7), 256, 0, stream>>>(emb, WihF, bF, proj);
    lstm_kernel<<<512, 256, 0, stream>>>(X, lens, proj, WhhF, W1, h0, c0, 0, zsum);
    proj_kernel<<<dim3(782, 7), 256, 0, stream>>>(emb, WihB, bB, proj);
    lstm_kernel<<<512, 256, 0, stream>>>(X, lens, proj, WhhB, W1, h0, c0, 1, zsum);
    mlp_kernel<<<1024, 256, 0, stream>>>(lens, zsum, b1, W2, b2, probs);
    viterbi_kernel<<<512, 64, 0, stream>>>(probs, lens, trans, out);
}

// Round 6
// 2012.191 us; speedup vs baseline: 1.1307x; 1.1307x over previous
//
#include <hip/hip_runtime.h>

#define V    50000
#define Bn   512
#define Ln   512
#define Hh   100     // per-direction hidden == EMB
#define G4   400     // 4*H gate rows
#define KK   20
#define NEGC -1e6f

// ---------------------------------------------------------------------------
// Kernel 1: vocabulary projection table (one direction).
// table[v][j] = emb[v,:].Wih[j,:] + b[j]   (GEMM M=50000, N=400, K=100)
// ---------------------------------------------------------------------------
__global__ __launch_bounds__(256) void proj_kernel(
    const float* __restrict__ emb,
    const float* __restrict__ Wih, const float* __restrict__ bias,
    float* __restrict__ out)
{
    const int v0 = blockIdx.x * 64;
    const int j0 = blockIdx.y * 64;

    __shared__ float As[100 * 68];   // [k][v], stride 68 (%32==4 -> b128 conflict-free)
    __shared__ float Bs[100 * 68];   // [k][j]
    const int tid = threadIdx.x;

    for (int i = tid; i < 6400; i += 256) {
        int r = i / 100;
        int k = i - r * 100;
        As[k * 68 + r] = (v0 + r < V)  ? emb[(size_t)(v0 + r) * 100 + k] : 0.f;
        Bs[k * 68 + r] = (j0 + r < G4) ? Wih[(j0 + r) * 100 + k]         : 0.f;
    }
    __syncthreads();

    const int tm = tid >> 4, tn = tid & 15;
    float acc[4][4];
#pragma unroll
    for (int i = 0; i < 4; ++i)
#pragma unroll
        for (int j = 0; j < 4; ++j) acc[i][j] = 0.f;

#pragma unroll 4
    for (int k = 0; k < 100; ++k) {
        float4 a = *(const float4*)&As[k * 68 + tm * 4];
        float4 b = *(const float4*)&Bs[k * 68 + tn * 4];
        acc[0][0] = fmaf(a.x, b.x, acc[0][0]); acc[0][1] = fmaf(a.x, b.y, acc[0][1]);
        acc[0][2] = fmaf(a.x, b.z, acc[0][2]); acc[0][3] = fmaf(a.x, b.w, acc[0][3]);
        acc[1][0] = fmaf(a.y, b.x, acc[1][0]); acc[1][1] = fmaf(a.y, b.y, acc[1][1]);
        acc[1][2] = fmaf(a.y, b.z, acc[1][2]); acc[1][3] = fmaf(a.y, b.w, acc[1][3]);
        acc[2][0] = fmaf(a.z, b.x, acc[2][0]); acc[2][1] = fmaf(a.z, b.y, acc[2][1]);
        acc[2][2] = fmaf(a.z, b.z, acc[2][2]); acc[2][3] = fmaf(a.z, b.w, acc[2][3]);
        acc[3][0] = fmaf(a.w, b.x, acc[3][0]); acc[3][1] = fmaf(a.w, b.y, acc[3][1]);
        acc[3][2] = fmaf(a.w, b.z, acc[3][2]); acc[3][3] = fmaf(a.w, b.w, acc[3][3]);
    }

#pragma unroll
    for (int i = 0; i < 4; ++i) {
        int v = v0 + tm * 4 + i;
        if (v < V) {
#pragma unroll
            for (int j = 0; j < 4; ++j) {
                int jj = j0 + tn * 4 + j;
                if (jj < G4) out[(size_t)v * G4 + jj] = acc[i][j] + bias[jj];
            }
        }
    }
}

// ---------------------------------------------------------------------------
// Kernel 2: LSTM recurrence, one direction. One block per batch element.
// 256 threads. Thread t owns gate row t (w0) and, for t<144, gate row 256+t
// (w1) of Whh in VGPRs. Threads 144..193 instead hold W1[t-144][dir*100..+100]
// in w1 and accumulate z = h_new . W1row (fused MLP first layer), one step
// delayed. dir=0 stores z; dir=1 accumulates (z += ...).
//
// amdgpu_waves_per_eu(2,2): R4 showed hipcc targeting 4 waves/EU (VGPR=116)
// and spilling the 200 weight floats -> 763 VALU instrs/step/wave vs ~330
// ideal. Grid is 2 blocks/CU (= 2 waves/EU) regardless, so pin the allocator
// there and keep weights in VGPRs (budget 256).
// ---------------------------------------------------------------------------
__device__ __forceinline__ float sigf(float x) { return 1.f / (1.f + expf(-x)); }
__device__ __forceinline__ float tanhfast(float x) { return 1.f - 2.f / (expf(2.f * x) + 1.f); }

__global__ __launch_bounds__(256)
__attribute__((amdgpu_waves_per_eu(2, 2)))
void lstm_kernel(
    const int* __restrict__ X, const int* __restrict__ lens,
    const float* __restrict__ proj, const float* __restrict__ Whh,
    const float* __restrict__ W1,
    const float* __restrict__ h0, const float* __restrict__ c0,
    const int dir, float* __restrict__ z)
{
    const int bid = blockIdx.x;
    const int b   = (bid < 256) ? bid : (767 - bid);   // pair long+short lens per CU
    const int len = lens[b];
    const int t   = threadIdx.x;
    const bool zth = (t >= 144 && t < 194);

    // ---- weights into registers ----
    float w0[100], w1[100];
    {
        const float4* W4 = (const float4*)(Whh + t * 100);
#pragma unroll
        for (int i = 0; i < 25; ++i) {
            float4 q = W4[i];
            w0[4*i] = q.x; w0[4*i+1] = q.y; w0[4*i+2] = q.z; w0[4*i+3] = q.w;
        }
        const float* src = (t < 144) ? (Whh + (256 + t) * 100)
                         : (t < 194) ? (W1 + (size_t)(t - 144) * 200 + dir * 100)
                                     : (Whh + 256 * 100);   // clamped, result unused
        const float4* W4b = (const float4*)src;
#pragma unroll
        for (int i = 0; i < 25; ++i) {
            float4 q = W4b[i];
            w1[4*i] = q.x; w1[4*i+1] = q.y; w1[4*i+2] = q.z; w1[4*i+3] = q.w;
        }
    }

    __shared__ float h_s[100];
    __shared__ float g_s[400];
    float c = 0.f;
    if (t < 100) {
        int base = (dir * Bn + b) * Hh + t;
        c = c0[base];
        h_s[t] = h0[base];
    }
    __syncthreads();

    const int lane = t & 63;
    int prevpos = 0;

    // position of step s (clamped into [0, Ln-1]; clamped values are only
    // ever prefetch targets for steps >= len, whose data is discarded)
    #define POS_OF(s) ({ int _p = dir ? (len - 1 - (s)) : (s); \
                         _p < 0 ? 0 : (_p > Ln - 1 ? Ln - 1 : _p); })

    // 2-deep proj prefetch pipeline: A = step s, B = step s+1
    float A0, A1, B0, B1;
    {
        int pA = POS_OF(0), pB = POS_OF(1);
        const float* prA = proj + (size_t)X[b * Ln + pA] * G4;
        const float* prB = proj + (size_t)X[b * Ln + pB] * G4;
        A0 = prA[t]; A1 = (t < 144) ? prA[256 + t] : 0.f;
        B0 = prB[t]; B1 = (t < 144) ? prB[256 + t] : 0.f;
    }

    for (int step = 0; step < len; ++step) {
        const int pos = dir ? (len - 1 - step) : step;

        // issue step+2 prefetch FIRST: ~full sweep of latency cover
        int p2 = POS_OF(step + 2);
        const float* pr2 = proj + (size_t)X[b * Ln + p2] * G4;
        float C0 = pr2[t];
        float C1 = (t < 144) ? pr2[256 + t] : 0.f;

        // dir=1: z accumulate-read, latency hides under the sweep
        float zprev = 0.f;
        if (dir && zth && step > 0)
            zprev = z[((size_t)b * Ln + prevpos) * 50 + (t - 144)];

        float vh0 = h_s[lane];                       // unconditional: readlane needs
        float vh1 = h_s[lane < 36 ? 64 + lane : 0];  // every lane's register valid

        // gate sweep: 4 independent FMA chains (2 per accumulator)
        float a0a = A0, a0b = 0.f, a1a = A1, a1b = 0.f;
#pragma unroll
        for (int k = 0; k < 100; k += 2) {
            float hk0 = __int_as_float(__builtin_amdgcn_readlane(
                __float_as_int(k < 64 ? vh0 : vh1), k & 63));
            float hk1 = __int_as_float(__builtin_amdgcn_readlane(
                __float_as_int((k + 1) < 64 ? vh0 : vh1), (k + 1) & 63));
            a0a = fmaf(hk0, w0[k],     a0a);
            a1a = fmaf(hk0, w1[k],     a1a);
            a0b = fmaf(hk1, w0[k + 1], a0b);
            a1b = fmaf(hk1, w1[k + 1], a1b);
        }
        float acc0 = a0a + a0b, acc1 = a1a + a1b;

        g_s[t] = acc0;
        if (t < 144) {
            g_s[256 + t] = acc1;
        } else if (zth && step > 0) {
            z[((size_t)b * Ln + prevpos) * 50 + (t - 144)] = acc1 + zprev;
        }
        __syncthreads();

        if (t < 100) {
            float gi = g_s[t], gf = g_s[100 + t], gg = g_s[200 + t], go = g_s[300 + t];
            float si = sigf(gi), sf = sigf(gf), so = sigf(go);
            float tg = tanhfast(gg);
            c = sf * c + si * tg;
            h_s[t] = so * tanhfast(c);
        }
        __syncthreads();

        A0 = B0; A1 = B1; B0 = C0; B1 = C1;
        prevpos = pos;
    }

    // epilogue: z for the final position (all lanes run the sweep; only
    // z-threads store — readlane ignores EXEC, so vh loads must be universal)
    {
        float zprev = 0.f;
        if (dir && zth)
            zprev = z[((size_t)b * Ln + prevpos) * 50 + (t - 144)];
        float vh0 = h_s[lane];
        float vh1 = h_s[lane < 36 ? 64 + lane : 0];
        float acc1 = 0.f;
#pragma unroll
        for (int k = 0; k < 100; ++k) {
            float hk = __int_as_float(__builtin_amdgcn_readlane(
                __float_as_int(k < 64 ? vh0 : vh1), k & 63));
            acc1 = fmaf(hk, w1[k], acc1);
        }
        if (zth)
            z[((size_t)b * Ln + prevpos) * 50 + (t - 144)] = acc1 + zprev;
    }
    #undef POS_OF
}

// ---------------------------------------------------------------------------
// Kernel 3: tiny MLP tail. probs = relu(zsum+b1) @ W2^T + b2, t < len only.
// One thread per (b,t). W2/b1/b2 accesses are thread-uniform -> s_loads.
// ---------------------------------------------------------------------------
__global__ __launch_bounds__(256) void mlp_kernel(
    const int* __restrict__ lens,
    const float* __restrict__ zsum,
    const float* __restrict__ b1, const float* __restrict__ W2,
    const float* __restrict__ b2, float* __restrict__ probs)
{
    const int gid = blockIdx.x * 256 + threadIdx.x;   // = b*512 + t
    const int b = gid >> 9, t = gid & 511;
    if (t >= lens[b]) return;

    float h[50];
    const float2* f2 = (const float2*)(zsum + (size_t)gid * 50);
#pragma unroll
    for (int j = 0; j < 25; ++j) {
        float2 a = f2[j];
        h[2*j]   = fmaxf(a.x + b1[2*j],   0.f);
        h[2*j+1] = fmaxf(a.y + b1[2*j+1], 0.f);
    }

    float o[20];
#pragma unroll
    for (int oo = 0; oo < 20; ++oo) {
        float acc = b2[oo];
#pragma unroll
        for (int j = 0; j < 50; ++j) acc = fmaf(h[j], W2[oo * 50 + j], acc);
        o[oo] = acc;
    }

    float4* P = (float4*)(probs + (size_t)gid * 20);
#pragma unroll
    for (int q = 0; q < 5; ++q)
        P[q] = make_float4(o[4*q], o[4*q+1], o[4*q+2], o[4*q+3]);
}

// ---------------------------------------------------------------------------
// Kernel 4: Viterbi. One wave per batch row; lanes 0..19 = tags.
// idx matrix in LDS; strict '>' ascending == jnp.argmax first-max.
// ---------------------------------------------------------------------------
__global__ __launch_bounds__(64) void viterbi_kernel(
    const float* __restrict__ probs, const int* __restrict__ lens,
    const float* __restrict__ trans, float* __restrict__ out)
{
    const int b    = blockIdx.x;
    const int lane = threadIdx.x;
    const int len  = lens[b];
    __shared__ unsigned char idx_s[Ln * KK];

    float tcol[20];
#pragma unroll
    for (int i = 0; i < 20; ++i)
        tcol[i] = (lane < 20) ? trans[i * 20 + lane] : 0.f;

    float alpha = (lane == 18) ? 0.f : NEGC;   // START = 18

    for (int t = 0; t < len; ++t) {
        float pv = (lane < 20) ? probs[((size_t)b * Ln + t) * KK + lane] : 0.f;
        float best = -3.4e38f; int bi = 0;
#pragma unroll
        for (int i = 0; i < 20; ++i) {
            float ai = __int_as_float(__builtin_amdgcn_readlane(__float_as_int(alpha), i));
            float v = ai + tcol[i];
            if (v > best) { best = v; bi = i; }
        }
        alpha = best + pv;
        if (lane < 20) idx_s[t * 20 + lane] = (unsigned char)bi;
    }

    float fin = alpha + ((lane < 20) ? trans[lane * 20 + 19] : 0.f);  // END = 19
    float best = -3.4e38f; int cur = 0;
#pragma unroll
    for (int j = 0; j < 20; ++j) {
        float v = __int_as_float(__builtin_amdgcn_readlane(__float_as_int(fin), j));
        if (v > best) { best = v; cur = j; }
    }
    if (lane == 0) out[b] = best;

    float* pout = out + Bn + (size_t)b * Ln;
    for (int tt = len + lane; tt < Ln; tt += 64) pout[tt] = -1.f;  // pads
    __syncthreads();

    if (lane == 0) {
        int c = cur;
        for (int t = len - 1; t >= 0; --t) {
            pout[t] = (float)c;
            c = idx_s[t * 20 + c];
        }
    }
}

// ---------------------------------------------------------------------------
extern "C" void kernel_launch(void* const* d_in, const int* in_sizes, int n_in,
                              void* d_out, int out_size, void* d_ws, size_t ws_size,
                              hipStream_t stream)
{
    const int*   X     = (const int*)  d_in[0];
    const int*   lens  = (const int*)  d_in[1];
    const float* emb   = (const float*)d_in[2];
    const float* WihF  = (const float*)d_in[3];
    const float* WhhF  = (const float*)d_in[4];
    const float* bF    = (const float*)d_in[5];
    const float* WihB  = (const float*)d_in[6];
    const float* WhhB  = (const float*)d_in[7];
    const float* bB    = (const float*)d_in[8];
    const float* h0    = (const float*)d_in[9];
    const float* c0    = (const float*)d_in[10];
    const float* W1    = (const float*)d_in[11];
    const float* b1    = (const float*)d_in[12];
    const float* W2    = (const float*)d_in[13];
    const float* b2    = (const float*)d_in[14];
    const float* trans = (const float*)d_in[15];
    float* out = (float*)d_out;

    // Workspace (floats): proj 20.0M (80 MB, rebuilt per dir; probs aliases it
    // after both LSTMs) | zsum 13.1M (52.4 MB).  Peak = 132.4 MB of d_ws.
    float* ws    = (float*)d_ws;
    float* proj  = ws;
    float* zsum  = ws + (size_t)V * G4;                    // +20,000,000 floats
    float* probs = ws;                                     // alias proj region

    proj_kernel<<<dim3(782, 7), 256, 0, stream>>>(emb, WihF, bF, proj);
    lstm_kernel<<<512, 256, 0, stream>>>(X, lens, proj, WhhF, W1, h0, c0, 0, zsum);
    proj_kernel<<<dim3(782, 7), 256, 0, stream>>>(emb, WihB, bB, proj);
    lstm_kernel<<<512, 256, 0, stream>>>(X, lens, proj, WhhB, W1, h0, c0, 1, zsum);
    mlp_kernel<<<1024, 256, 0, stream>>>(lens, zsum, b1, W2, b2, probs);
    viterbi_kernel<<<512, 64, 0, stream>>>(probs, lens, trans, out);
}